// Round 3
// baseline (415.979 us; speedup 1.0000x reference)
//
#include <hip/hip_runtime.h>
#include <stdint.h>

#define T_SEQ 2048
#define HIDDEN 4096
#define NHEAD 32
#define NKV 8
#define HDIM 128
#define QKVN 6144  // (32 + 2*8) * 128

typedef __bf16 bf16x8 __attribute__((ext_vector_type(8)));
typedef float f32x4 __attribute__((ext_vector_type(4)));
typedef unsigned short u16;
typedef u16 u16x8 __attribute__((ext_vector_type(8)));
typedef u16 u16x4 __attribute__((ext_vector_type(4)));

__device__ __forceinline__ u16 f2bf(float f) {
  uint32_t u = __builtin_bit_cast(uint32_t, f);
  u = (u + 0x7fffu + ((u >> 16) & 1u)) >> 16;
  return (u16)u;
}
__device__ __forceinline__ float bf2f(u16 h) {
  uint32_t u = ((uint32_t)h) << 16;
  return __builtin_bit_cast(float, u);
}

// async global->LDS, 16B per lane. LDS dest must be wave-uniform; HW adds lane*16.
__device__ __forceinline__ void gload16(const void* g, void* l) {
  __builtin_amdgcn_global_load_lds(
      (__attribute__((address_space(1))) void*)(uintptr_t)g,
      (__attribute__((address_space(3))) void*)(uintptr_t)l, 16, 0, 0);
}

// ---------------- fp32 -> bf16 convert ----------------
__global__ void cvt_f32_bf16(const float* __restrict__ in, u16* __restrict__ out, int n) {
  int i = (blockIdx.x * blockDim.x + threadIdx.x) * 4;
  int stride = gridDim.x * blockDim.x * 4;
  for (; i < n; i += stride) {
    float4 v = *(const float4*)(in + i);
    u16x4 o;
    o.x = f2bf(v.x); o.y = f2bf(v.y); o.z = f2bf(v.z); o.w = f2bf(v.w);
    *(u16x4*)(out + i) = o;
  }
}

// ---------------- RoPE (neox), in-place on bf16 qkv ----------------
__global__ void rope_kernel(u16* __restrict__ qkv, const int* __restrict__ pos) {
  int idx = blockIdx.x * blockDim.x + threadIdx.x;
  if (idx >= T_SEQ * 40 * 64) return;
  int i = idx & 63;
  int head = (idx >> 6) % 40;
  int t = idx / (40 * 64);
  int base = head < NHEAD ? head * HDIM : NHEAD * HDIM + (head - NHEAD) * HDIM;
  float p = (float)pos[t];
  float inv_freq = exp2f(-(float)i * (13.287712379549449f / 64.0f));
  float ang = p * inv_freq;
  float s, c;
  sincosf(ang, &s, &c);
  u16* p1 = qkv + (size_t)t * QKVN + base + i;
  u16* p2 = p1 + 64;
  float x1 = bf2f(*p1), x2 = bf2f(*p2);
  *p1 = f2bf(x1 * c - x2 * s);
  *p2 = f2bf(x2 * c + x1 * s);
}

// ---------------- 8-phase NT GEMM: C[M][N] = A[M][K]*B[N][K]^T ----------------
// BM=128, BN=256, BK=64, 512 thr = 8 waves (2M x 4N), per-wave 64x64 out.
// LDS 96KB static: A 2x[128x64], B 2x[256x64] bf16, XOR-swizzled 16B slots.
// Counted vmcnt, raw s_barrier (no __syncthreads -> no vmcnt(0) drain).
__device__ __forceinline__ void storeC(float* p, float v) { *p = v; }
__device__ __forceinline__ void storeC(u16* p, float v) { *p = f2bf(v); }

template <typename OutT>
__global__ void __launch_bounds__(512, 2)
gemm8p(const u16* __restrict__ A, const u16* __restrict__ B,
       OutT* __restrict__ C, int M, int N, int K, int nbx) {
  __shared__ u16 As_[2][128 * 64];
  __shared__ u16 Bs_[2][256 * 64];

  const int tid = threadIdx.x;
  const int lane = tid & 63;
  const int w = tid >> 6;
  const int wr = w >> 2;   // 0..1
  const int wc = w & 3;    // 0..3
  const int l15 = lane & 15, lg = lane >> 4;

  // bijective XCD swizzle (grid % 8 == 0 for both call sites)
  const int qq = gridDim.x >> 3;
  const int swz = (blockIdx.x & 7) * qq + (blockIdx.x >> 3);
  const int bx = swz % nbx, by = swz / nbx;
  const int bm = by * 128, bn = bx * 256;

  // staging lane invariants: round = 64 LDS rows; lane covers row j, phys slot lane&7,
  // which holds logical slot ss (pre-swizzled global source, rule #21).
  const int j = w * 8 + (lane >> 3);              // 0..63
  const int ss = (lane & 7) ^ ((lane >> 3) & 7);  // logical 16B slot fetched
  // A rowmap: LDS row (r*64+j) holds global row m = ((j>>5)&1)*64 + r*32 + (j&31)
  const u16* a_src = A + (size_t)(bm + ((j >> 5) & 1) * 64 + (j & 31)) * K + ss * 8;
  // B natural: LDS row (r*64+j) holds global col n = r*64 + j
  const u16* b_src = B + (size_t)(bn + j) * K + ss * 8;

  // read-side invariants (swizzle key = LDS row & 7 = l15 & 7)
  const int axor = l15 & 7;
  const int a_rd = (wr * 32 + l15) * 64;
  const int b_rd = (wc * 64 + l15) * 64;
  const int sl0 = ((0 * 4 + lg) ^ axor) * 8;  // kk=0 slot
  const int sl1 = ((1 * 4 + lg) ^ axor) * 8;  // kk=1 slot

  f32x4 acc[4][4] = {};
  bf16x8 bfr[4][2];

#define AG(r_, t_) (a_src + (size_t)(r_) * 32 * K + (size_t)(t_) * 64)
#define BG(r_, t_) (b_src + (size_t)(r_) * 64 * K + (size_t)(t_) * 64)
#define AL(r_, p_) (&As_[p_][((r_) * 64 + w * 8) * 64])
#define BL(r_, p_) (&Bs_[p_][((r_) * 64 + w * 8) * 64])
#define BARRIER() asm volatile("s_barrier" ::: "memory")
#define WAITBAR(n_) asm volatile("s_waitcnt vmcnt(" #n_ ")\n\ts_barrier" ::: "memory")

  // prologue: stage tile 0 into buf 0, full drain once
  gload16(BG(0, 0), BL(0, 0));
  gload16(BG(1, 0), BL(1, 0));
  gload16(BG(2, 0), BL(2, 0));
  gload16(BG(3, 0), BL(3, 0));
  gload16(AG(0, 0), AL(0, 0));
  gload16(AG(1, 0), AL(1, 0));
  WAITBAR(0);

  const int NT = K >> 6;
  for (int t = 0; t < NT; ++t) {
    const int c = t & 1, p = c ^ 1;
    const bool more = (t + 1) < NT;
    const u16* Ac = &As_[c][0];
    const u16* Bc = &Bs_[c][0];

#define MFMA_PHASE(q_)                                                          \
  {                                                                             \
    const u16* ap = Ac + a_rd + ((q_) >> 1) * 4096 + ((q_) & 1) * 1024;         \
    bf16x8 a0 = *(const bf16x8*)(ap + sl0);                                     \
    bf16x8 a1 = *(const bf16x8*)(ap + sl1);                                     \
    __builtin_amdgcn_s_setprio(1);                                              \
    _Pragma("unroll") for (int ni = 0; ni < 4; ++ni) {                          \
      acc[q_][ni] = __builtin_amdgcn_mfma_f32_16x16x32_bf16(a0, bfr[ni][0], acc[q_][ni], 0, 0, 0); \
      acc[q_][ni] = __builtin_amdgcn_mfma_f32_16x16x32_bf16(a1, bfr[ni][1], acc[q_][ni], 0, 0, 0); \
    }                                                                           \
    __builtin_amdgcn_s_setprio(0);                                              \
  }

    // ---- phase 0: B-frag reads + quadrant 0 ----
    if (more) { gload16(BG(0, t + 1), BL(0, p)); gload16(BG(1, t + 1), BL(1, p)); }
#pragma unroll
    for (int ni = 0; ni < 4; ++ni) {
      bfr[ni][0] = *(const bf16x8*)(Bc + b_rd + ni * 1024 + sl0);
      bfr[ni][1] = *(const bf16x8*)(Bc + b_rd + ni * 1024 + sl1);
    }
    MFMA_PHASE(0);
    BARRIER();

    // ---- phase 1 ----
    if (more) { gload16(BG(2, t + 1), BL(2, p)); gload16(BG(3, t + 1), BL(3, p)); }
    MFMA_PHASE(1);
    if (more) { WAITBAR(4); } else { WAITBAR(0); }  // A1(t) safe before phase 2

    // ---- phase 2 ----
    if (more) { gload16(AG(0, t + 1), AL(0, p)); gload16(AG(1, t + 1), AL(1, p)); }
    MFMA_PHASE(2);
    BARRIER();

    // ---- phase 3 ----
    MFMA_PHASE(3);
    if (more) { WAITBAR(1); } else { BARRIER(); }  // B all + A0 of t+1 safe
#undef MFMA_PHASE
  }

  // epilogue
#pragma unroll
  for (int mi = 0; mi < 4; ++mi)
#pragma unroll
    for (int ni = 0; ni < 4; ++ni)
#pragma unroll
      for (int r = 0; r < 4; ++r) {
        int row = bm + wr * 64 + mi * 16 + lg * 4 + r;
        int col = bn + wc * 64 + ni * 16 + l15;
        storeC(&C[(size_t)row * N + col], acc[mi][ni][r]);
      }
#undef AG
#undef BG
#undef AL
#undef BL
}

// ---------------- causal GQA flash attention (unchanged from R2) ----------------
__global__ void __launch_bounds__(256)
attn_kernel(const u16* __restrict__ qkv, u16* __restrict__ out) {
  __shared__ u16 Ksh[2][64 * 128];
  __shared__ u16 Vsh[2][128 * 64];
  __shared__ u16 Psh[4][16 * 64];

  const int tid = threadIdx.x;
  const int lane = tid & 63;
  const int w = tid >> 6;
  const int l15 = lane & 15, lg = lane >> 4;

  const int bid = blockIdx.x;
  const int kvh = bid & 7;
  const int hg = (bid >> 3) & 3;
  const int qi = 31 - (bid >> 5);
  const int h = kvh * 4 + hg;
  const int q0 = qi * 64;
  const int nt = qi + 1;

  const u16* Kg = qkv + NHEAD * HDIM + kvh * HDIM;
  const u16* Vg = qkv + (NHEAD + NKV) * HDIM + kvh * HDIM;

  bf16x8 qa[4];
  {
    const u16* qrow = qkv + (size_t)(q0 + w * 16 + l15) * QKVN + h * HDIM + lg * 8;
#pragma unroll
    for (int ks = 0; ks < 4; ++ks) qa[ks] = *(const bf16x8*)(qrow + ks * 32);
  }

  f32x4 acc_o[8] = {};
  float m[4], lsum[4];
#pragma unroll
  for (int r = 0; r < 4; ++r) { m[r] = -1e30f; lsum[r] = 0.f; }

  const float scale = 0.088388347648318447f;

#define STAGE_K(kv0, p)                                                        \
  {                                                                            \
    _Pragma("unroll") for (int rnd = 0; rnd < 4; ++rnd) {                      \
      int cc = rnd * 256 + tid;                                                \
      int krow = cc >> 4, kslot = cc & 15;                                     \
      gload16(Kg + (size_t)((kv0) + krow) * QKVN + (kslot ^ (krow & 7)) * 8,   \
              &Ksh[p][(rnd * 256 + w * 64) * 8]);                              \
    }                                                                          \
  }
#define LOAD_V(kv0, vr)                                                        \
  {                                                                            \
    _Pragma("unroll") for (int rnd = 0; rnd < 4; ++rnd) {                      \
      int cc = rnd * 256 + tid;                                                \
      int vrow = cc >> 4, d0 = (cc & 15) * 8;                                  \
      vr[rnd] = *(const u16x8*)(Vg + (size_t)((kv0) + vrow) * QKVN + d0);      \
    }                                                                          \
  }
#define WRITE_V(vr, p)                                                         \
  {                                                                            \
    _Pragma("unroll") for (int rnd = 0; rnd < 4; ++rnd) {                      \
      int cc = rnd * 256 + tid;                                                \
      int vrow = cc >> 4, d0 = (cc & 15) * 8;                                  \
      _Pragma("unroll") for (int j = 0; j < 8; ++j) {                          \
        int d = d0 + j;                                                        \
        Vsh[p][d * 64 + (((vrow >> 3) ^ (d & 7) ^ ((d >> 3) & 7)) * 8) +       \
               (vrow & 7)] = vr[rnd][j];                                       \
      }                                                                        \
    }                                                                          \
  }

  u16x8 vreg[4];
  STAGE_K(0, 0);
  LOAD_V(0, vreg);
  WRITE_V(vreg, 0);
  __syncthreads();

  for (int t = 0; t < nt; ++t) {
    const int p = t & 1;
    const int kv0 = t * 64;
    const bool more = (t + 1 < nt);
    u16x8 vnext[4];
    if (more) {
      STAGE_K(kv0 + 64, p ^ 1);
      LOAD_V(kv0 + 64, vnext);
    }

    f32x4 s[4] = {};
#pragma unroll
    for (int ks = 0; ks < 4; ++ks) {
#pragma unroll
      for (int n = 0; n < 4; ++n) {
        int row16 = n * 16 + l15;
        bf16x8 kf = *(const bf16x8*)&Ksh[p][row16 * 128 +
                                            (((ks * 4 + lg) ^ (row16 & 7)) * 8)];
        s[n] = __builtin_amdgcn_mfma_f32_16x16x32_bf16(qa[ks], kf, s[n], 0, 0, 0);
      }
    }

    const bool diag = (t == nt - 1);
    float alpha[4];
#pragma unroll
    for (int r = 0; r < 4; ++r) {
      int tq = q0 + w * 16 + lg * 4 + r;
      float mx = -1e30f;
#pragma unroll
      for (int n = 0; n < 4; ++n) {
        float v = s[n][r] * scale;
        if (diag && (kv0 + n * 16 + l15) > tq) v = -1e30f;
        s[n][r] = v;
        mx = fmaxf(mx, v);
      }
#pragma unroll
      for (int msk = 1; msk < 16; msk <<= 1) mx = fmaxf(mx, __shfl_xor(mx, msk, 64));
      float mn = fmaxf(m[r], mx);
      alpha[r] = __expf(m[r] - mn);
      m[r] = mn;
      float ps = 0.f;
#pragma unroll
      for (int n = 0; n < 4; ++n) {
        float pv = __expf(s[n][r] - mn);
        s[n][r] = pv;
        ps += pv;
      }
#pragma unroll
      for (int msk = 1; msk < 16; msk <<= 1) ps += __shfl_xor(ps, msk, 64);
      lsum[r] = lsum[r] * alpha[r] + ps;
      int prow = lg * 4 + r;
#pragma unroll
      for (int n = 0; n < 4; ++n)
        Psh[w][prow * 64 + (((n * 2 + (l15 >> 3)) ^ (prow & 7)) * 8) + (l15 & 7)] =
            f2bf(s[n][r]);
    }
#pragma unroll
    for (int f = 0; f < 8; ++f)
#pragma unroll
      for (int r = 0; r < 4; ++r) acc_o[f][r] *= alpha[r];

#pragma unroll
    for (int ks = 0; ks < 2; ++ks) {
      bf16x8 pa = *(const bf16x8*)&Psh[w][l15 * 64 + (((ks * 4 + lg) ^ (l15 & 7)) * 8)];
#pragma unroll
      for (int nd = 0; nd < 8; ++nd) {
        int d = nd * 16 + l15;
        bf16x8 bv = *(const bf16x8*)&Vsh[p][d * 64 +
                        (((ks * 4 + lg) ^ (d & 7) ^ ((d >> 3) & 7)) * 8)];
        acc_o[nd] = __builtin_amdgcn_mfma_f32_16x16x32_bf16(pa, bv, acc_o[nd], 0, 0, 0);
      }
    }

    if (more) WRITE_V(vnext, p ^ 1);
    __syncthreads();
  }

#pragma unroll
  for (int nd = 0; nd < 8; ++nd)
#pragma unroll
    for (int r = 0; r < 4; ++r) {
      int row = q0 + w * 16 + lg * 4 + r;
      int col = h * HDIM + nd * 16 + l15;
      out[(size_t)row * (NHEAD * HDIM) + col] = f2bf(acc_o[nd][r] / lsum[r]);
    }
#undef STAGE_K
#undef LOAD_V
#undef WRITE_V
}

// ---------------- launcher ----------------
extern "C" void kernel_launch(void* const* d_in, const int* in_sizes, int n_in,
                              void* d_out, int out_size, void* d_ws, size_t ws_size,
                              hipStream_t stream) {
  const float* hs   = (const float*)d_in[0];
  const int*   pos  = (const int*)d_in[1];
  const float* wqkv = (const float*)d_in[2];
  const float* wo   = (const float*)d_in[3];
  float* out = (float*)d_out;
  uint8_t* ws = (uint8_t*)d_ws;

  if (ws_size < 142606336u) return;
  u16* hs_bf   = (u16*)(ws + 0);
  u16* wqkv_bf = (u16*)(ws + 16777216u);
  u16* wo_bf   = (u16*)(ws + 67108864u);
  u16* qkv_bf  = (u16*)(ws + 100663296u);
  u16* attn_bf = (u16*)(ws + 125829120u);

  cvt_f32_bf16<<<2048, 256, 0, stream>>>(hs, hs_bf, T_SEQ * HIDDEN);
  cvt_f32_bf16<<<2048, 256, 0, stream>>>(wqkv, wqkv_bf, QKVN * HIDDEN);
  cvt_f32_bf16<<<2048, 256, 0, stream>>>(wo, wo_bf, HIDDEN * HIDDEN);

  // QKV: M=2048 (16 x BM=128), N=6144 (24 x BN=256) -> 384 blocks
  gemm8p<u16><<<384, 512, 0, stream>>>(hs_bf, wqkv_bf, qkv_bf,
                                       T_SEQ, QKVN, HIDDEN, 24);

  rope_kernel<<<(T_SEQ * 40 * 64) / 256, 256, 0, stream>>>(qkv_bf, pos);

  attn_kernel<<<1024, 256, 0, stream>>>(qkv_bf, attn_bf);

  // Wo: M=2048 (16), N=4096 (16) -> 256 blocks, exact fill
  gemm8p<float><<<256, 512, 0, stream>>>(attn_bf, wo_bf, out,
                                         T_SEQ, HIDDEN, HIDDEN, 16);
}

// Round 4
// 382.447 us; speedup vs baseline: 1.0877x; 1.0877x over previous
//
#include <hip/hip_runtime.h>
#include <stdint.h>

#define T_SEQ 2048
#define HIDDEN 4096
#define NHEAD 32
#define NKV 8
#define HDIM 128
#define QKVN 6144  // (32 + 2*8) * 128

typedef __bf16 bf16x8 __attribute__((ext_vector_type(8)));
typedef float f32x4 __attribute__((ext_vector_type(4)));
typedef unsigned short u16;
typedef u16 u16x8 __attribute__((ext_vector_type(8)));
typedef u16 u16x4 __attribute__((ext_vector_type(4)));

__device__ __forceinline__ u16 f2bf(float f) {
  uint32_t u = __builtin_bit_cast(uint32_t, f);
  u = (u + 0x7fffu + ((u >> 16) & 1u)) >> 16;
  return (u16)u;
}
__device__ __forceinline__ float bf2f(u16 h) {
  uint32_t u = ((uint32_t)h) << 16;
  return __builtin_bit_cast(float, u);
}

// async global->LDS, 16B per lane. LDS dest must be wave-uniform; HW adds lane*16.
__device__ __forceinline__ void gload16(const void* g, void* l) {
  __builtin_amdgcn_global_load_lds(
      (__attribute__((address_space(1))) void*)(uintptr_t)g,
      (__attribute__((address_space(3))) void*)(uintptr_t)l, 16, 0, 0);
}

// ---------------- fp32 -> bf16 convert ----------------
__global__ void cvt_f32_bf16(const float* __restrict__ in, u16* __restrict__ out, int n) {
  int i = (blockIdx.x * blockDim.x + threadIdx.x) * 4;
  int stride = gridDim.x * blockDim.x * 4;
  for (; i < n; i += stride) {
    float4 v = *(const float4*)(in + i);
    u16x4 o;
    o.x = f2bf(v.x); o.y = f2bf(v.y); o.z = f2bf(v.z); o.w = f2bf(v.w);
    *(u16x4*)(out + i) = o;
  }
}

// ---------------- RoPE (neox), in-place on bf16 qkv ----------------
__global__ void rope_kernel(u16* __restrict__ qkv, const int* __restrict__ pos) {
  int idx = blockIdx.x * blockDim.x + threadIdx.x;
  if (idx >= T_SEQ * 40 * 64) return;
  int i = idx & 63;
  int head = (idx >> 6) % 40;
  int t = idx / (40 * 64);
  int base = head < NHEAD ? head * HDIM : NHEAD * HDIM + (head - NHEAD) * HDIM;
  float p = (float)pos[t];
  float inv_freq = exp2f(-(float)i * (13.287712379549449f / 64.0f));
  float ang = p * inv_freq;
  float s, c;
  sincosf(ang, &s, &c);
  u16* p1 = qkv + (size_t)t * QKVN + base + i;
  u16* p2 = p1 + 64;
  float x1 = bf2f(*p1), x2 = bf2f(*p2);
  *p1 = f2bf(x1 * c - x2 * s);
  *p2 = f2bf(x2 * c + x1 * s);
}

// ---------------- 4-phase NT GEMM, triple-buffered depth-2 pipeline ----------
// C[M][N] = A[M][K]*B[N][K]^T. BM=128, BN=256, BK=64, 512 thr = 8 waves (2Mx4N).
// LDS 144KB: 3 bufs x (A 128x64 + B 256x64) bf16, XOR-swizzled 16B slots.
// All 6 gload_lds for tile t+2 issue at phase 0 of tile t; WAITBAR(vmcnt(6)) at
// end of phase 3 drains exactly tile t+1's loads (7-phase issue->consume cover).
// Per-wave vmcnt is group-safe: each wave waits, THEN the barrier releases.
__device__ __forceinline__ void storeC(float* p, float v) { *p = v; }
__device__ __forceinline__ void storeC(u16* p, float v) { *p = f2bf(v); }

template <typename OutT>
__global__ void __launch_bounds__(512, 1)
gemm8p(const u16* __restrict__ A, const u16* __restrict__ B,
       OutT* __restrict__ C, int M, int N, int K,
       int nbx, int rw, int rh) {
  __shared__ u16 As_[3][128 * 64];
  __shared__ u16 Bs_[3][256 * 64];

  const int tid = threadIdx.x;
  const int lane = tid & 63;
  const int w = tid >> 6;
  const int wr = w >> 2;   // 0..1
  const int wc = w & 3;    // 0..3
  const int l15 = lane & 15, lg = lane >> 4;

  // compact per-XCD rectangle: chunk c = bid&7 owns an rh x rw block-rect,
  // column-major within (consecutive i share bx -> share B-panel in time).
  const int c8 = blockIdx.x & 7;
  const int i8 = blockIdx.x >> 3;
  const int rpr = nbx / rw;  // rects per block-row
  const int by = (c8 / rpr) * rh + (i8 % rh);
  const int bx = (c8 % rpr) * rw + (i8 / rh);
  const int bm = by * 128, bn = bx * 256;

  // staging lane invariants (pre-swizzled global source, rule #21)
  const int j = w * 8 + (lane >> 3);              // LDS row within 64-row round
  const int ss = (lane & 7) ^ ((lane >> 3) & 7);  // logical 16B slot fetched
  // A rowmap: LDS row (r*64+j) holds global row m = ((j>>5)&1)*64 + r*32 + (j&31)
  const u16* a_src = A + (size_t)(bm + ((j >> 5) & 1) * 64 + (j & 31)) * K + ss * 8;
  // B natural: LDS row (r*64+j) holds global col n = r*64 + j
  const u16* b_src = B + (size_t)(bn + j) * K + ss * 8;

  // read-side invariants (swizzle key = LDS row & 7 = l15 & 7)
  const int axor = l15 & 7;
  const int a_rd = (wr * 32 + l15) * 64;
  const int b_rd = (wc * 64 + l15) * 64;
  const int sl0 = ((0 * 4 + lg) ^ axor) * 8;  // kk=0 slot
  const int sl1 = ((1 * 4 + lg) ^ axor) * 8;  // kk=1 slot

  f32x4 acc[4][4] = {};
  bf16x8 bfr[4][2];

#define AG(r_, t_) (a_src + (size_t)(r_) * 32 * K + (size_t)(t_) * 64)
#define BG(r_, t_) (b_src + (size_t)(r_) * 64 * K + (size_t)(t_) * 64)
#define AL(r_, p_) (&As_[p_][((r_) * 64 + w * 8) * 64])
#define BL(r_, p_) (&Bs_[p_][((r_) * 64 + w * 8) * 64])
#define BARRIER() asm volatile("s_barrier" ::: "memory")
#define WAITBAR(n_) asm volatile("s_waitcnt vmcnt(" #n_ ")\n\ts_barrier" ::: "memory")
#define STAGE6(t_, p_)                                                         \
  {                                                                            \
    gload16(BG(0, t_), BL(0, p_));                                             \
    gload16(BG(1, t_), BL(1, p_));                                             \
    gload16(BG(2, t_), BL(2, p_));                                             \
    gload16(BG(3, t_), BL(3, p_));                                             \
    gload16(AG(0, t_), AL(0, p_));                                             \
    gload16(AG(1, t_), AL(1, p_));                                             \
  }

  // prologue: stage tiles 0 and 1; drain tile 0 (oldest 6 of 12)
  STAGE6(0, 0);
  STAGE6(1, 1);
  WAITBAR(6);

  const int NT = K >> 6;
  int cur = 0;
  for (int t = 0; t < NT; ++t) {
    const u16* Ac = &As_[cur][0];
    const u16* Bc = &Bs_[cur][0];
    const int st = (cur == 0) ? 2 : cur - 1;  // (cur+2)%3

#define MFMA_PHASE(q_)                                                          \
  {                                                                             \
    const u16* ap = Ac + a_rd + ((q_) >> 1) * 4096 + ((q_) & 1) * 1024;         \
    bf16x8 a0 = *(const bf16x8*)(ap + sl0);                                     \
    bf16x8 a1 = *(const bf16x8*)(ap + sl1);                                     \
    __builtin_amdgcn_s_setprio(1);                                              \
    _Pragma("unroll") for (int ni = 0; ni < 4; ++ni) {                          \
      acc[q_][ni] = __builtin_amdgcn_mfma_f32_16x16x32_bf16(a0, bfr[ni][0], acc[q_][ni], 0, 0, 0); \
      acc[q_][ni] = __builtin_amdgcn_mfma_f32_16x16x32_bf16(a1, bfr[ni][1], acc[q_][ni], 0, 0, 0); \
    }                                                                           \
    __builtin_amdgcn_s_setprio(0);                                              \
  }

    // ---- phase 0: issue ALL of tile t+2's loads, B-frag reads, quadrant 0 ----
    if (t + 2 < NT) STAGE6(t + 2, st);
#pragma unroll
    for (int ni = 0; ni < 4; ++ni) {
      bfr[ni][0] = *(const bf16x8*)(Bc + b_rd + ni * 1024 + sl0);
      bfr[ni][1] = *(const bf16x8*)(Bc + b_rd + ni * 1024 + sl1);
    }
    MFMA_PHASE(0);
    BARRIER();

    // ---- phase 1 ----
    MFMA_PHASE(1);
    BARRIER();

    // ---- phase 2 ----
    MFMA_PHASE(2);
    BARRIER();

    // ---- phase 3 ----
    MFMA_PHASE(3);
    if (t + 2 < NT) {
      WAITBAR(6);        // drain tile t+1's 6 loads; t+2's 6 float across
    } else if (t + 1 < NT) {
      WAITBAR(0);        // last prefetched tile: drain fully
    } else {
      BARRIER();
    }
#undef MFMA_PHASE
    cur = (cur == 2) ? 0 : cur + 1;
  }

  // epilogue
#pragma unroll
  for (int mi = 0; mi < 4; ++mi)
#pragma unroll
    for (int ni = 0; ni < 4; ++ni)
#pragma unroll
      for (int r = 0; r < 4; ++r) {
        int row = bm + wr * 64 + mi * 16 + lg * 4 + r;
        int col = bn + wc * 64 + ni * 16 + l15;
        storeC(&C[(size_t)row * N + col], acc[mi][ni][r]);
      }
#undef AG
#undef BG
#undef AL
#undef BL
#undef STAGE6
}

// ---------------- causal GQA flash attention (unchanged) ----------------
__global__ void __launch_bounds__(256)
attn_kernel(const u16* __restrict__ qkv, u16* __restrict__ out) {
  __shared__ u16 Ksh[2][64 * 128];
  __shared__ u16 Vsh[2][128 * 64];
  __shared__ u16 Psh[4][16 * 64];

  const int tid = threadIdx.x;
  const int lane = tid & 63;
  const int w = tid >> 6;
  const int l15 = lane & 15, lg = lane >> 4;

  const int bid = blockIdx.x;
  const int kvh = bid & 7;
  const int hg = (bid >> 3) & 3;
  const int qi = 31 - (bid >> 5);
  const int h = kvh * 4 + hg;
  const int q0 = qi * 64;
  const int nt = qi + 1;

  const u16* Kg = qkv + NHEAD * HDIM + kvh * HDIM;
  const u16* Vg = qkv + (NHEAD + NKV) * HDIM + kvh * HDIM;

  bf16x8 qa[4];
  {
    const u16* qrow = qkv + (size_t)(q0 + w * 16 + l15) * QKVN + h * HDIM + lg * 8;
#pragma unroll
    for (int ks = 0; ks < 4; ++ks) qa[ks] = *(const bf16x8*)(qrow + ks * 32);
  }

  f32x4 acc_o[8] = {};
  float m[4], lsum[4];
#pragma unroll
  for (int r = 0; r < 4; ++r) { m[r] = -1e30f; lsum[r] = 0.f; }

  const float scale = 0.088388347648318447f;

#define STAGE_K(kv0, p)                                                        \
  {                                                                            \
    _Pragma("unroll") for (int rnd = 0; rnd < 4; ++rnd) {                      \
      int cc = rnd * 256 + tid;                                                \
      int krow = cc >> 4, kslot = cc & 15;                                     \
      gload16(Kg + (size_t)((kv0) + krow) * QKVN + (kslot ^ (krow & 7)) * 8,   \
              &Ksh[p][(rnd * 256 + w * 64) * 8]);                              \
    }                                                                          \
  }
#define LOAD_V(kv0, vr)                                                        \
  {                                                                            \
    _Pragma("unroll") for (int rnd = 0; rnd < 4; ++rnd) {                      \
      int cc = rnd * 256 + tid;                                                \
      int vrow = cc >> 4, d0 = (cc & 15) * 8;                                  \
      vr[rnd] = *(const u16x8*)(Vg + (size_t)((kv0) + vrow) * QKVN + d0);      \
    }                                                                          \
  }
#define WRITE_V(vr, p)                                                         \
  {                                                                            \
    _Pragma("unroll") for (int rnd = 0; rnd < 4; ++rnd) {                      \
      int cc = rnd * 256 + tid;                                                \
      int vrow = cc >> 4, d0 = (cc & 15) * 8;                                  \
      _Pragma("unroll") for (int j = 0; j < 8; ++j) {                          \
        int d = d0 + j;                                                        \
        Vsh[p][d * 64 + (((vrow >> 3) ^ (d & 7) ^ ((d >> 3) & 7)) * 8) +       \
               (vrow & 7)] = vr[rnd][j];                                       \
      }                                                                        \
    }                                                                          \
  }

  u16x8 vreg[4];
  STAGE_K(0, 0);
  LOAD_V(0, vreg);
  WRITE_V(vreg, 0);
  __syncthreads();

  for (int t = 0; t < nt; ++t) {
    const int p = t & 1;
    const int kv0 = t * 64;
    const bool more = (t + 1 < nt);
    u16x8 vnext[4];
    if (more) {
      STAGE_K(kv0 + 64, p ^ 1);
      LOAD_V(kv0 + 64, vnext);
    }

    f32x4 s[4] = {};
#pragma unroll
    for (int ks = 0; ks < 4; ++ks) {
#pragma unroll
      for (int n = 0; n < 4; ++n) {
        int row16 = n * 16 + l15;
        bf16x8 kf = *(const bf16x8*)&Ksh[p][row16 * 128 +
                                            (((ks * 4 + lg) ^ (row16 & 7)) * 8)];
        s[n] = __builtin_amdgcn_mfma_f32_16x16x32_bf16(qa[ks], kf, s[n], 0, 0, 0);
      }
    }

    const bool diag = (t == nt - 1);
    float alpha[4];
#pragma unroll
    for (int r = 0; r < 4; ++r) {
      int tq = q0 + w * 16 + lg * 4 + r;
      float mx = -1e30f;
#pragma unroll
      for (int n = 0; n < 4; ++n) {
        float v = s[n][r] * scale;
        if (diag && (kv0 + n * 16 + l15) > tq) v = -1e30f;
        s[n][r] = v;
        mx = fmaxf(mx, v);
      }
#pragma unroll
      for (int msk = 1; msk < 16; msk <<= 1) mx = fmaxf(mx, __shfl_xor(mx, msk, 64));
      float mn = fmaxf(m[r], mx);
      alpha[r] = __expf(m[r] - mn);
      m[r] = mn;
      float ps = 0.f;
#pragma unroll
      for (int n = 0; n < 4; ++n) {
        float pv = __expf(s[n][r] - mn);
        s[n][r] = pv;
        ps += pv;
      }
#pragma unroll
      for (int msk = 1; msk < 16; msk <<= 1) ps += __shfl_xor(ps, msk, 64);
      lsum[r] = lsum[r] * alpha[r] + ps;
      int prow = lg * 4 + r;
#pragma unroll
      for (int n = 0; n < 4; ++n)
        Psh[w][prow * 64 + (((n * 2 + (l15 >> 3)) ^ (prow & 7)) * 8) + (l15 & 7)] =
            f2bf(s[n][r]);
    }
#pragma unroll
    for (int f = 0; f < 8; ++f)
#pragma unroll
      for (int r = 0; r < 4; ++r) acc_o[f][r] *= alpha[r];

#pragma unroll
    for (int ks = 0; ks < 2; ++ks) {
      bf16x8 pa = *(const bf16x8*)&Psh[w][l15 * 64 + (((ks * 4 + lg) ^ (l15 & 7)) * 8)];
#pragma unroll
      for (int nd = 0; nd < 8; ++nd) {
        int d = nd * 16 + l15;
        bf16x8 bv = *(const bf16x8*)&Vsh[p][d * 64 +
                        (((ks * 4 + lg) ^ (d & 7) ^ ((d >> 3) & 7)) * 8)];
        acc_o[nd] = __builtin_amdgcn_mfma_f32_16x16x32_bf16(pa, bv, acc_o[nd], 0, 0, 0);
      }
    }

    if (more) WRITE_V(vnext, p ^ 1);
    __syncthreads();
  }

#pragma unroll
  for (int nd = 0; nd < 8; ++nd)
#pragma unroll
    for (int r = 0; r < 4; ++r) {
      int row = q0 + w * 16 + lg * 4 + r;
      int col = h * HDIM + nd * 16 + l15;
      out[(size_t)row * (NHEAD * HDIM) + col] = f2bf(acc_o[nd][r] / lsum[r]);
    }
#undef STAGE_K
#undef LOAD_V
#undef WRITE_V
}

// ---------------- launcher ----------------
extern "C" void kernel_launch(void* const* d_in, const int* in_sizes, int n_in,
                              void* d_out, int out_size, void* d_ws, size_t ws_size,
                              hipStream_t stream) {
  const float* hs   = (const float*)d_in[0];
  const int*   pos  = (const int*)d_in[1];
  const float* wqkv = (const float*)d_in[2];
  const float* wo   = (const float*)d_in[3];
  float* out = (float*)d_out;
  uint8_t* ws = (uint8_t*)d_ws;

  if (ws_size < 142606336u) return;
  u16* hs_bf   = (u16*)(ws + 0);
  u16* wqkv_bf = (u16*)(ws + 16777216u);
  u16* wo_bf   = (u16*)(ws + 67108864u);
  u16* qkv_bf  = (u16*)(ws + 100663296u);
  u16* attn_bf = (u16*)(ws + 125829120u);

  cvt_f32_bf16<<<2048, 256, 0, stream>>>(hs, hs_bf, T_SEQ * HIDDEN);
  cvt_f32_bf16<<<2048, 256, 0, stream>>>(wqkv, wqkv_bf, QKVN * HIDDEN);
  cvt_f32_bf16<<<2048, 256, 0, stream>>>(wo, wo_bf, HIDDEN * HIDDEN);

  // QKV: 16 by x 24 bx = 384 blocks; per-XCD rect 8x6
  gemm8p<u16><<<384, 512, 0, stream>>>(hs_bf, wqkv_bf, qkv_bf,
                                       T_SEQ, QKVN, HIDDEN, 24, 6, 8);

  rope_kernel<<<(T_SEQ * 40 * 64) / 256, 256, 0, stream>>>(qkv_bf, pos);

  attn_kernel<<<1024, 256, 0, stream>>>(qkv_bf, attn_bf);

  // Wo: 16 by x 16 bx = 256 blocks; per-XCD rect 8x4
  gemm8p<float><<<256, 512, 0, stream>>>(attn_bf, wo_bf, out,
                                         T_SEQ, HIDDEN, HIDDEN, 16, 4, 8);
}

// Round 5
// 373.878 us; speedup vs baseline: 1.1126x; 1.0229x over previous
//
#include <hip/hip_runtime.h>
#include <stdint.h>

#define T_SEQ 2048
#define HIDDEN 4096
#define NHEAD 32
#define NKV 8
#define HDIM 128
#define QKVN 6144  // (32 + 2*8) * 128

typedef __bf16 bf16x8 __attribute__((ext_vector_type(8)));
typedef float f32x4 __attribute__((ext_vector_type(4)));
typedef unsigned short u16;
typedef u16 u16x8 __attribute__((ext_vector_type(8)));
typedef u16 u16x4 __attribute__((ext_vector_type(4)));

__device__ __forceinline__ u16 f2bf(float f) {
  uint32_t u = __builtin_bit_cast(uint32_t, f);
  u = (u + 0x7fffu + ((u >> 16) & 1u)) >> 16;
  return (u16)u;
}
__device__ __forceinline__ float bf2f(u16 h) {
  uint32_t u = ((uint32_t)h) << 16;
  return __builtin_bit_cast(float, u);
}

// async global->LDS, 16B per lane. LDS dest must be wave-uniform; HW adds lane*16.
__device__ __forceinline__ void gload16(const void* g, void* l) {
  __builtin_amdgcn_global_load_lds(
      (__attribute__((address_space(1))) void*)(uintptr_t)g,
      (__attribute__((address_space(3))) void*)(uintptr_t)l, 16, 0, 0);
}

// ---------------- fp32 -> bf16 convert ----------------
__global__ void cvt_f32_bf16(const float* __restrict__ in, u16* __restrict__ out, int n) {
  int i = (blockIdx.x * blockDim.x + threadIdx.x) * 4;
  int stride = gridDim.x * blockDim.x * 4;
  for (; i < n; i += stride) {
    float4 v = *(const float4*)(in + i);
    u16x4 o;
    o.x = f2bf(v.x); o.y = f2bf(v.y); o.z = f2bf(v.z); o.w = f2bf(v.w);
    *(u16x4*)(out + i) = o;
  }
}

// ---------------- RoPE (neox), in-place on bf16 qkv ----------------
__global__ void rope_kernel(u16* __restrict__ qkv, const int* __restrict__ pos) {
  int idx = blockIdx.x * blockDim.x + threadIdx.x;
  if (idx >= T_SEQ * 40 * 64) return;
  int i = idx & 63;
  int head = (idx >> 6) % 40;
  int t = idx / (40 * 64);
  int base = head < NHEAD ? head * HDIM : NHEAD * HDIM + (head - NHEAD) * HDIM;
  float p = (float)pos[t];
  float inv_freq = exp2f(-(float)i * (13.287712379549449f / 64.0f));
  float ang = p * inv_freq;
  float s, c;
  sincosf(ang, &s, &c);
  u16* p1 = qkv + (size_t)t * QKVN + base + i;
  u16* p2 = p1 + 64;
  float x1 = bf2f(*p1), x2 = bf2f(*p2);
  *p1 = f2bf(x1 * c - x2 * s);
  *p2 = f2bf(x2 * c + x1 * s);
}

// ---------------- NT GEMM: C = A[M,K] * B[N,K]^T, BK=32 fat-phase ------------
// BM=BN=128, 256 thr = 4 waves (2Mx2N), per-wave 64x64 out, 16 MFMA per K-tile
// between single barriers. LDS 48KB = 3 bufs x (A 8KB + B 8KB) -> 3 blocks/CU.
// Stage 2 K-tiles ahead (4 gload_lds/thread/tile), boundary s_waitcnt vmcnt(4).
// 16B slots double-XOR swizzled: phys = slot ^ (row&3) ^ ((row>>2)&3).
__device__ __forceinline__ void storeC(float* p, float v) { *p = v; }
__device__ __forceinline__ void storeC(u16* p, float v) { *p = f2bf(v); }

template <typename OutT>
__global__ void __launch_bounds__(256, 3)
gemm_k32(const u16* __restrict__ A, const u16* __restrict__ B,
         OutT* __restrict__ C, int M, int N, int K,
         int nbx, int rw, int rh) {
  __shared__ u16 As_[3][128 * 32];
  __shared__ u16 Bs_[3][128 * 32];

  const int tid = threadIdx.x;
  const int lane = tid & 63;
  const int w = tid >> 6;          // 0..3
  const int wr = w >> 1, wc = w & 1;
  const int l15 = lane & 15, lg = lane >> 4;

  // compact per-XCD rectangle: chunk c8 owns rh x rw block-rect, col-major within
  const int c8 = blockIdx.x & 7;
  const int i8 = blockIdx.x >> 3;
  const int rpr = nbx / rw;
  const int by = (c8 / rpr) * rh + (i8 % rh);
  const int bx = (c8 % rpr) * rw + (i8 / rh);
  const int bm = by * 128, bn = bx * 128;

  // staging: unit u = g*256 + w*64 + lane; LDS row r = u>>2, phys slot u&3,
  // which must hold logical slot s = (u&3)^(r&3)^((r>>2)&3)  (rule #21)
  const u16* asrc[2];
  const u16* bsrc[2];
#pragma unroll
  for (int g = 0; g < 2; ++g) {
    int u = g * 256 + w * 64 + lane;
    int r = u >> 2;
    int s = (u & 3) ^ (r & 3) ^ ((r >> 2) & 3);
    asrc[g] = A + (size_t)(bm + r) * K + s * 8;
    bsrc[g] = B + (size_t)(bn + r) * K + s * 8;
  }

  // read-side: row = base + mi*16; phys slot = lg ^ (l15&3) ^ ((l15>>2)&3)
  // (mi*16, wr*64, wc*64 don't touch the low bits -> per-thread constant)
  const int sl = (lg ^ (l15 & 3) ^ ((l15 >> 2) & 3)) * 8;
  const int a_rd = (wr * 64 + l15) * 32 + sl;
  const int b_rd = (wc * 64 + l15) * 32 + sl;

  f32x4 acc[4][4] = {};

#define BARRIER() asm volatile("s_barrier" ::: "memory")
#define WAITBAR(n_) asm volatile("s_waitcnt vmcnt(" #n_ ")\n\ts_barrier" ::: "memory")
#define STAGE(t_, p_)                                                          \
  {                                                                            \
    gload16(asrc[0] + (size_t)(t_) * 32, &As_[p_][w * 512]);                   \
    gload16(asrc[1] + (size_t)(t_) * 32, &As_[p_][2048 + w * 512]);            \
    gload16(bsrc[0] + (size_t)(t_) * 32, &Bs_[p_][w * 512]);                   \
    gload16(bsrc[1] + (size_t)(t_) * 32, &Bs_[p_][2048 + w * 512]);            \
  }

  // prologue: stage tiles 0 and 1; drain tile 0 (oldest 4 of 8)
  STAGE(0, 0);
  STAGE(1, 1);
  WAITBAR(4);

  const int NT = K >> 5;
  int cur = 0;
  for (int t = 0; t < NT; ++t) {
    const int st = (cur == 0) ? 2 : cur - 1;  // (cur+2)%3
    if (t + 2 < NT) STAGE(t + 2, st);

    const u16* Ab = &As_[cur][a_rd];
    const u16* Bb = &Bs_[cur][b_rd];
    bf16x8 a0 = *(const bf16x8*)(Ab);
    bf16x8 a1 = *(const bf16x8*)(Ab + 512);
    bf16x8 a2 = *(const bf16x8*)(Ab + 1024);
    bf16x8 a3 = *(const bf16x8*)(Ab + 1536);
    __builtin_amdgcn_s_setprio(1);
#pragma unroll
    for (int ni = 0; ni < 4; ++ni) {
      bf16x8 b = *(const bf16x8*)(Bb + ni * 512);
      acc[0][ni] = __builtin_amdgcn_mfma_f32_16x16x32_bf16(a0, b, acc[0][ni], 0, 0, 0);
      acc[1][ni] = __builtin_amdgcn_mfma_f32_16x16x32_bf16(a1, b, acc[1][ni], 0, 0, 0);
      acc[2][ni] = __builtin_amdgcn_mfma_f32_16x16x32_bf16(a2, b, acc[2][ni], 0, 0, 0);
      acc[3][ni] = __builtin_amdgcn_mfma_f32_16x16x32_bf16(a3, b, acc[3][ni], 0, 0, 0);
    }
    __builtin_amdgcn_s_setprio(0);

    if (t + 2 < NT) {
      WAITBAR(4);     // drain tile t+1's 4 loads; t+2's float across
    } else if (t + 1 < NT) {
      WAITBAR(0);     // last prefetched tile: drain fully
    }
    cur = (cur == 2) ? 0 : cur + 1;
  }

  // epilogue
#pragma unroll
  for (int mi = 0; mi < 4; ++mi)
#pragma unroll
    for (int ni = 0; ni < 4; ++ni)
#pragma unroll
      for (int r = 0; r < 4; ++r) {
        int row = bm + wr * 64 + mi * 16 + lg * 4 + r;
        int col = bn + wc * 64 + ni * 16 + l15;
        storeC(&C[(size_t)row * N + col], acc[mi][ni][r]);
      }
#undef STAGE
#undef WAITBAR
#undef BARRIER
}

// ---------------- causal GQA flash attention (unchanged) ----------------
__global__ void __launch_bounds__(256)
attn_kernel(const u16* __restrict__ qkv, u16* __restrict__ out) {
  __shared__ u16 Ksh[2][64 * 128];
  __shared__ u16 Vsh[2][128 * 64];
  __shared__ u16 Psh[4][16 * 64];

  const int tid = threadIdx.x;
  const int lane = tid & 63;
  const int w = tid >> 6;
  const int l15 = lane & 15, lg = lane >> 4;

  const int bid = blockIdx.x;
  const int kvh = bid & 7;
  const int hg = (bid >> 3) & 3;
  const int qi = 31 - (bid >> 5);
  const int h = kvh * 4 + hg;
  const int q0 = qi * 64;
  const int nt = qi + 1;

  const u16* Kg = qkv + NHEAD * HDIM + kvh * HDIM;
  const u16* Vg = qkv + (NHEAD + NKV) * HDIM + kvh * HDIM;

  bf16x8 qa[4];
  {
    const u16* qrow = qkv + (size_t)(q0 + w * 16 + l15) * QKVN + h * HDIM + lg * 8;
#pragma unroll
    for (int ks = 0; ks < 4; ++ks) qa[ks] = *(const bf16x8*)(qrow + ks * 32);
  }

  f32x4 acc_o[8] = {};
  float m[4], lsum[4];
#pragma unroll
  for (int r = 0; r < 4; ++r) { m[r] = -1e30f; lsum[r] = 0.f; }

  const float scale = 0.088388347648318447f;

#define STAGE_K(kv0, p)                                                        \
  {                                                                            \
    _Pragma("unroll") for (int rnd = 0; rnd < 4; ++rnd) {                      \
      int cc = rnd * 256 + tid;                                                \
      int krow = cc >> 4, kslot = cc & 15;                                     \
      gload16(Kg + (size_t)((kv0) + krow) * QKVN + (kslot ^ (krow & 7)) * 8,   \
              &Ksh[p][(rnd * 256 + w * 64) * 8]);                              \
    }                                                                          \
  }
#define LOAD_V(kv0, vr)                                                        \
  {                                                                            \
    _Pragma("unroll") for (int rnd = 0; rnd < 4; ++rnd) {                      \
      int cc = rnd * 256 + tid;                                                \
      int vrow = cc >> 4, d0 = (cc & 15) * 8;                                  \
      vr[rnd] = *(const u16x8*)(Vg + (size_t)((kv0) + vrow) * QKVN + d0);      \
    }                                                                          \
  }
#define WRITE_V(vr, p)                                                         \
  {                                                                            \
    _Pragma("unroll") for (int rnd = 0; rnd < 4; ++rnd) {                      \
      int cc = rnd * 256 + tid;                                                \
      int vrow = cc >> 4, d0 = (cc & 15) * 8;                                  \
      _Pragma("unroll") for (int j = 0; j < 8; ++j) {                          \
        int d = d0 + j;                                                        \
        Vsh[p][d * 64 + (((vrow >> 3) ^ (d & 7) ^ ((d >> 3) & 7)) * 8) +       \
               (vrow & 7)] = vr[rnd][j];                                       \
      }                                                                        \
    }                                                                          \
  }

  u16x8 vreg[4];
  STAGE_K(0, 0);
  LOAD_V(0, vreg);
  WRITE_V(vreg, 0);
  __syncthreads();

  for (int t = 0; t < nt; ++t) {
    const int p = t & 1;
    const int kv0 = t * 64;
    const bool more = (t + 1 < nt);
    u16x8 vnext[4];
    if (more) {
      STAGE_K(kv0 + 64, p ^ 1);
      LOAD_V(kv0 + 64, vnext);
    }

    f32x4 s[4] = {};
#pragma unroll
    for (int ks = 0; ks < 4; ++ks) {
#pragma unroll
      for (int n = 0; n < 4; ++n) {
        int row16 = n * 16 + l15;
        bf16x8 kf = *(const bf16x8*)&Ksh[p][row16 * 128 +
                                            (((ks * 4 + lg) ^ (row16 & 7)) * 8)];
        s[n] = __builtin_amdgcn_mfma_f32_16x16x32_bf16(qa[ks], kf, s[n], 0, 0, 0);
      }
    }

    const bool diag = (t == nt - 1);
    float alpha[4];
#pragma unroll
    for (int r = 0; r < 4; ++r) {
      int tq = q0 + w * 16 + lg * 4 + r;
      float mx = -1e30f;
#pragma unroll
      for (int n = 0; n < 4; ++n) {
        float v = s[n][r] * scale;
        if (diag && (kv0 + n * 16 + l15) > tq) v = -1e30f;
        s[n][r] = v;
        mx = fmaxf(mx, v);
      }
#pragma unroll
      for (int msk = 1; msk < 16; msk <<= 1) mx = fmaxf(mx, __shfl_xor(mx, msk, 64));
      float mn = fmaxf(m[r], mx);
      alpha[r] = __expf(m[r] - mn);
      m[r] = mn;
      float ps = 0.f;
#pragma unroll
      for (int n = 0; n < 4; ++n) {
        float pv = __expf(s[n][r] - mn);
        s[n][r] = pv;
        ps += pv;
      }
#pragma unroll
      for (int msk = 1; msk < 16; msk <<= 1) ps += __shfl_xor(ps, msk, 64);
      lsum[r] = lsum[r] * alpha[r] + ps;
      int prow = lg * 4 + r;
#pragma unroll
      for (int n = 0; n < 4; ++n)
        Psh[w][prow * 64 + (((n * 2 + (l15 >> 3)) ^ (prow & 7)) * 8) + (l15 & 7)] =
            f2bf(s[n][r]);
    }
#pragma unroll
    for (int f = 0; f < 8; ++f)
#pragma unroll
      for (int r = 0; r < 4; ++r) acc_o[f][r] *= alpha[r];

#pragma unroll
    for (int ks = 0; ks < 2; ++ks) {
      bf16x8 pa = *(const bf16x8*)&Psh[w][l15 * 64 + (((ks * 4 + lg) ^ (l15 & 7)) * 8)];
#pragma unroll
      for (int nd = 0; nd < 8; ++nd) {
        int d = nd * 16 + l15;
        bf16x8 bv = *(const bf16x8*)&Vsh[p][d * 64 +
                        (((ks * 4 + lg) ^ (d & 7) ^ ((d >> 3) & 7)) * 8)];
        acc_o[nd] = __builtin_amdgcn_mfma_f32_16x16x32_bf16(pa, bv, acc_o[nd], 0, 0, 0);
      }
    }

    if (more) WRITE_V(vnext, p ^ 1);
    __syncthreads();
  }

#pragma unroll
  for (int nd = 0; nd < 8; ++nd)
#pragma unroll
    for (int r = 0; r < 4; ++r) {
      int row = q0 + w * 16 + lg * 4 + r;
      int col = h * HDIM + nd * 16 + l15;
      out[(size_t)row * (NHEAD * HDIM) + col] = f2bf(acc_o[nd][r] / lsum[r]);
    }
#undef STAGE_K
#undef LOAD_V
#undef WRITE_V
}

// ---------------- launcher ----------------
extern "C" void kernel_launch(void* const* d_in, const int* in_sizes, int n_in,
                              void* d_out, int out_size, void* d_ws, size_t ws_size,
                              hipStream_t stream) {
  const float* hs   = (const float*)d_in[0];
  const int*   pos  = (const int*)d_in[1];
  const float* wqkv = (const float*)d_in[2];
  const float* wo   = (const float*)d_in[3];
  float* out = (float*)d_out;
  uint8_t* ws = (uint8_t*)d_ws;

  if (ws_size < 142606336u) return;
  u16* hs_bf   = (u16*)(ws + 0);
  u16* wqkv_bf = (u16*)(ws + 16777216u);
  u16* wo_bf   = (u16*)(ws + 67108864u);
  u16* qkv_bf  = (u16*)(ws + 100663296u);
  u16* attn_bf = (u16*)(ws + 125829120u);

  cvt_f32_bf16<<<2048, 256, 0, stream>>>(hs, hs_bf, T_SEQ * HIDDEN);
  cvt_f32_bf16<<<2048, 256, 0, stream>>>(wqkv, wqkv_bf, QKVN * HIDDEN);
  cvt_f32_bf16<<<2048, 256, 0, stream>>>(wo, wo_bf, HIDDEN * HIDDEN);

  // QKV: 16 by x 48 bx = 768 blocks = exactly 3/CU; per-XCD rect 8x12
  gemm_k32<u16><<<768, 256, 0, stream>>>(hs_bf, wqkv_bf, qkv_bf,
                                         T_SEQ, QKVN, HIDDEN, 48, 12, 8);

  rope_kernel<<<(T_SEQ * 40 * 64) / 256, 256, 0, stream>>>(qkv_bf, pos);

  attn_kernel<<<1024, 256, 0, stream>>>(qkv_bf, attn_bf);

  // Wo: 16 by x 32 bx = 512 blocks = exactly 2/CU; per-XCD rect 8x8
  gemm_k32<float><<<512, 256, 0, stream>>>(attn_bf, wo_bf, out,
                                           T_SEQ, HIDDEN, HIDDEN, 32, 8, 8);
}

// Round 6
// 353.911 us; speedup vs baseline: 1.1754x; 1.0564x over previous
//
#include <hip/hip_runtime.h>
#include <stdint.h>

#define T_SEQ 2048
#define HIDDEN 4096
#define NHEAD 32
#define NKV 8
#define HDIM 128
#define QKVN 6144  // (32 + 2*8) * 128

typedef __bf16 bf16x8 __attribute__((ext_vector_type(8)));
typedef float f32x4 __attribute__((ext_vector_type(4)));
typedef unsigned short u16;
typedef u16 u16x8 __attribute__((ext_vector_type(8)));
typedef u16 u16x4 __attribute__((ext_vector_type(4)));

__device__ __forceinline__ u16 f2bf(float f) {
  uint32_t u = __builtin_bit_cast(uint32_t, f);
  u = (u + 0x7fffu + ((u >> 16) & 1u)) >> 16;
  return (u16)u;
}
__device__ __forceinline__ float bf2f(u16 h) {
  uint32_t u = ((uint32_t)h) << 16;
  return __builtin_bit_cast(float, u);
}

// async global->LDS, 16B per lane. LDS dest must be wave-uniform; HW adds lane*16.
__device__ __forceinline__ void gload16(const void* g, void* l) {
  __builtin_amdgcn_global_load_lds(
      (__attribute__((address_space(1))) void*)(uintptr_t)g,
      (__attribute__((address_space(3))) void*)(uintptr_t)l, 16, 0, 0);
}

// ---------------- fp32 -> bf16 convert ----------------
__global__ void cvt_f32_bf16(const float* __restrict__ in, u16* __restrict__ out, int n) {
  int i = (blockIdx.x * blockDim.x + threadIdx.x) * 4;
  int stride = gridDim.x * blockDim.x * 4;
  for (; i < n; i += stride) {
    float4 v = *(const float4*)(in + i);
    u16x4 o;
    o.x = f2bf(v.x); o.y = f2bf(v.y); o.z = f2bf(v.z); o.w = f2bf(v.w);
    *(u16x4*)(out + i) = o;
  }
}

// ---------------- RoPE (neox), in-place on bf16 qkv ----------------
__global__ void rope_kernel(u16* __restrict__ qkv, const int* __restrict__ pos) {
  int idx = blockIdx.x * blockDim.x + threadIdx.x;
  if (idx >= T_SEQ * 40 * 64) return;
  int i = idx & 63;
  int head = (idx >> 6) % 40;
  int t = idx / (40 * 64);
  int base = head < NHEAD ? head * HDIM : NHEAD * HDIM + (head - NHEAD) * HDIM;
  float p = (float)pos[t];
  float inv_freq = exp2f(-(float)i * (13.287712379549449f / 64.0f));
  float ang = p * inv_freq;
  float s, c;
  sincosf(ang, &s, &c);
  u16* p1 = qkv + (size_t)t * QKVN + base + i;
  u16* p2 = p1 + 64;
  float x1 = bf2f(*p1), x2 = bf2f(*p2);
  *p1 = f2bf(x1 * c - x2 * s);
  *p2 = f2bf(x2 * c + x1 * s);
}

// -------- 256x256 NT GEMM, 8 waves, per-wave 128x64 (AI 42.7), BK=64 --------
// 4 phases per K-tile; K-tile v in buf[v&1]. Stage schedule (race-free, each
// overwrite barrier-separated from its last reader):
//   p0: read B-frags(8)+A-q0(4); stage A0(v+1)->alt   [alt dead since prev p3]
//   p1: read A-q1; stage A1(v+1)->alt, B0(v+2)->cur   [cur.B last read p0]
//   p2: read A-q2; stage B1(v+2)->cur
//   p3: read A-q3; MFMA; s_waitcnt vmcnt(4)+barrier   [keeps only B(v+2) in flight]
// Optional fused tail: blocks >= nGemm convert fp32->bf16 (fills idle CUs).
__device__ __forceinline__ void storeC(float* p, float v) { *p = v; }
__device__ __forceinline__ void storeC(u16* p, float v) { *p = f2bf(v); }
__device__ __forceinline__ f32x4 mfma16(bf16x8 a, bf16x8 b, f32x4 c) {
  return __builtin_amdgcn_mfma_f32_16x16x32_bf16(a, b, c, 0, 0, 0);
}

template <typename OutT, bool FUSED>
__global__ void __launch_bounds__(512, 2)
gemm256(const u16* __restrict__ A, const u16* __restrict__ B,
        OutT* __restrict__ C0, OutT* __restrict__ C1,
        int N, int K, int NT, int sliceBlocks, int nGemm,
        int nbx, int rw, int rh,
        const float* __restrict__ cvt_in, u16* __restrict__ cvt_out, int cvt_n4) {
  if (FUSED && (int)blockIdx.x >= nGemm) {
    int i = (blockIdx.x - nGemm) * blockDim.x + threadIdx.x;
    int stride = (gridDim.x - nGemm) * blockDim.x;
    for (; i < cvt_n4; i += stride) {
      float4 v = ((const float4*)cvt_in)[i];
      u16x4 o;
      o.x = f2bf(v.x); o.y = f2bf(v.y); o.z = f2bf(v.z); o.w = f2bf(v.w);
      ((u16x4*)cvt_out)[i] = o;
    }
    return;
  }

  __shared__ u16 As_[2][256 * 64];
  __shared__ u16 Bs_[2][256 * 64];

  const int tid = threadIdx.x;
  const int lane = tid & 63;
  const int w = tid >> 6;            // 0..7
  const int wr = w >> 2, wc = w & 3; // 2M x 4N waves, per-wave 128x64
  const int l15 = lane & 15, lg = lane >> 4;

  const int bid = blockIdx.x;
  const int slice = bid / sliceBlocks;
  const int wi = bid % sliceBlocks;
  const int k0 = slice * (NT << 6);
  OutT* __restrict__ C = slice ? C1 : C0;

  // compact per-XCD rectangle
  const int c8 = wi & 7, i8 = wi >> 3;
  const int rpr = nbx / rw;
  const int by = (c8 / rpr) * rh + (i8 % rh);
  const int bx = (c8 % rpr) * rw + (i8 / rh);
  const int bm = by * 256, bn = bx * 256;

  // staging: half = 128 rows x 64 cols = 1024 16B-units; unit u: row=u>>3,
  // phys slot u&7 holds logical slot (u&7)^(row&7) (pre-swizzled source, #21)
  const int u_lo = w * 64 + lane, u_hi = u_lo + 512;
  const int r0 = u_lo >> 3, s0 = (u_lo & 7) ^ (r0 & 7);
  const int r1 = u_hi >> 3, s1 = (u_hi & 7) ^ (r1 & 7);
  const u16* a0s0 = A + (size_t)(bm + r0) * K + k0 + s0 * 8;
  const u16* a0s1 = A + (size_t)(bm + r1) * K + k0 + s1 * 8;
  const u16* a1s0 = A + (size_t)(bm + 128 + r0) * K + k0 + s0 * 8;
  const u16* a1s1 = A + (size_t)(bm + 128 + r1) * K + k0 + s1 * 8;
  const u16* b0s0 = B + (size_t)(bn + r0) * K + k0 + s0 * 8;
  const u16* b0s1 = B + (size_t)(bn + r1) * K + k0 + s1 * 8;
  const u16* b1s0 = B + (size_t)(bn + 128 + r0) * K + k0 + s0 * 8;
  const u16* b1s1 = B + (size_t)(bn + 128 + r1) * K + k0 + s1 * 8;

  // read side: row&7 == l15&7 for all frags (mi*16, wr*128, wc*64 ≡ 0 mod 8)
  const int ax = l15 & 7;
  const int sl0 = (lg ^ ax) * 8;        // kk=0
  const int sl1 = ((4 + lg) ^ ax) * 8;  // kk=1
  const int a_row = (wr * 128 + l15) * 64;
  const int b_row = (wc * 64 + l15) * 64;

  f32x4 acc[8][4] = {};
  bf16x8 bfr[4][2];

#define BARRIER() asm volatile("s_barrier" ::: "memory")
#define WAITBAR(n_) asm volatile("s_waitcnt vmcnt(" #n_ ")\n\ts_barrier" ::: "memory")
#define STAGE_HALF(p0_, p1_, dst_, t_)                                         \
  {                                                                            \
    gload16((p0_) + (size_t)(t_) * 64, (dst_) + (size_t)w * 512);              \
    gload16((p1_) + (size_t)(t_) * 64, (dst_) + 4096 + (size_t)w * 512);       \
  }

  // prologue: A(0),B(0) -> buf0; B(1) -> buf1; drain all but B(1)
  STAGE_HALF(a0s0, a0s1, &As_[0][0], 0);
  STAGE_HALF(a1s0, a1s1, &As_[0][8192], 0);
  STAGE_HALF(b0s0, b0s1, &Bs_[0][0], 0);
  STAGE_HALF(b1s0, b1s1, &Bs_[0][8192], 0);
  STAGE_HALF(b0s0, b0s1, &Bs_[1][0], 1);
  STAGE_HALF(b1s0, b1s1, &Bs_[1][8192], 1);
  WAITBAR(4);

  for (int v = 0; v < NT; ++v) {
    const int cur = v & 1, alt = cur ^ 1;
    const u16* Ac = &As_[cur][0];
    const u16* Bc = &Bs_[cur][0];
    const bool s1ok = (v + 1) < NT, s2ok = (v + 2) < NT;

#define MFMA_QUAD(p_, A0_, A1_, A2_, A3_)                                      \
    __builtin_amdgcn_s_setprio(1);                                             \
    _Pragma("unroll") for (int ni = 0; ni < 4; ++ni) {                         \
      acc[2 * (p_)][ni] = mfma16(A0_, bfr[ni][0], acc[2 * (p_)][ni]);          \
      acc[2 * (p_)][ni] = mfma16(A1_, bfr[ni][1], acc[2 * (p_)][ni]);          \
      acc[2 * (p_) + 1][ni] = mfma16(A2_, bfr[ni][0], acc[2 * (p_) + 1][ni]);  \
      acc[2 * (p_) + 1][ni] = mfma16(A3_, bfr[ni][1], acc[2 * (p_) + 1][ni]);  \
    }                                                                          \
    __builtin_amdgcn_s_setprio(0);

    // ---- phase 0 ----
    {
#pragma unroll
      for (int ni = 0; ni < 4; ++ni) {
        bfr[ni][0] = *(const bf16x8*)&Bc[b_row + ni * 1024 + sl0];
        bfr[ni][1] = *(const bf16x8*)&Bc[b_row + ni * 1024 + sl1];
      }
      bf16x8 f0 = *(const bf16x8*)&Ac[a_row + 0 * 1024 + sl0];
      bf16x8 f1 = *(const bf16x8*)&Ac[a_row + 0 * 1024 + sl1];
      bf16x8 f2 = *(const bf16x8*)&Ac[a_row + 1 * 1024 + sl0];
      bf16x8 f3 = *(const bf16x8*)&Ac[a_row + 1 * 1024 + sl1];
      if (s1ok) STAGE_HALF(a0s0, a0s1, &As_[alt][0], v + 1);
      BARRIER();
      MFMA_QUAD(0, f0, f1, f2, f3);
      BARRIER();
    }
    // ---- phase 1 ----
    {
      bf16x8 f0 = *(const bf16x8*)&Ac[a_row + 2 * 1024 + sl0];
      bf16x8 f1 = *(const bf16x8*)&Ac[a_row + 2 * 1024 + sl1];
      bf16x8 f2 = *(const bf16x8*)&Ac[a_row + 3 * 1024 + sl0];
      bf16x8 f3 = *(const bf16x8*)&Ac[a_row + 3 * 1024 + sl1];
      if (s1ok) STAGE_HALF(a1s0, a1s1, &As_[alt][8192], v + 1);
      if (s2ok) STAGE_HALF(b0s0, b0s1, &Bs_[cur][0], v + 2);
      BARRIER();
      MFMA_QUAD(1, f0, f1, f2, f3);
      BARRIER();
    }
    // ---- phase 2 ----
    {
      bf16x8 f0 = *(const bf16x8*)&Ac[a_row + 4 * 1024 + sl0];
      bf16x8 f1 = *(const bf16x8*)&Ac[a_row + 4 * 1024 + sl1];
      bf16x8 f2 = *(const bf16x8*)&Ac[a_row + 5 * 1024 + sl0];
      bf16x8 f3 = *(const bf16x8*)&Ac[a_row + 5 * 1024 + sl1];
      if (s2ok) STAGE_HALF(b1s0, b1s1, &Bs_[cur][8192], v + 2);
      BARRIER();
      MFMA_QUAD(2, f0, f1, f2, f3);
      BARRIER();
    }
    // ---- phase 3 ----
    {
      bf16x8 f0 = *(const bf16x8*)&Ac[a_row + 6 * 1024 + sl0];
      bf16x8 f1 = *(const bf16x8*)&Ac[a_row + 6 * 1024 + sl1];
      bf16x8 f2 = *(const bf16x8*)&Ac[a_row + 7 * 1024 + sl0];
      bf16x8 f3 = *(const bf16x8*)&Ac[a_row + 7 * 1024 + sl1];
      BARRIER();
      MFMA_QUAD(3, f0, f1, f2, f3);
      if (s2ok) { WAITBAR(4); } else { WAITBAR(0); }
    }
#undef MFMA_QUAD
  }

  // epilogue
#pragma unroll
  for (int mi = 0; mi < 8; ++mi)
#pragma unroll
    for (int ni = 0; ni < 4; ++ni)
#pragma unroll
      for (int r = 0; r < 4; ++r) {
        int row = bm + wr * 128 + mi * 16 + lg * 4 + r;
        int col = bn + wc * 64 + ni * 16 + l15;
        storeC(&C[(size_t)row * N + col], acc[mi][ni][r]);
      }
#undef STAGE_HALF
#undef WAITBAR
#undef BARRIER
}

// ---------------- split-K reduce: out += part ----------------
__global__ void reduce_add(float* __restrict__ out, const float* __restrict__ part, int n4) {
  int i = blockIdx.x * blockDim.x + threadIdx.x;
  int stride = gridDim.x * blockDim.x;
  for (; i < n4; i += stride) {
    float4 a = ((const float4*)out)[i];
    float4 b = ((const float4*)part)[i];
    a.x += b.x; a.y += b.y; a.z += b.z; a.w += b.w;
    ((float4*)out)[i] = a;
  }
}

// ---------------- causal GQA flash attention (unchanged) ----------------
__global__ void __launch_bounds__(256)
attn_kernel(const u16* __restrict__ qkv, u16* __restrict__ out) {
  __shared__ u16 Ksh[2][64 * 128];
  __shared__ u16 Vsh[2][128 * 64];
  __shared__ u16 Psh[4][16 * 64];

  const int tid = threadIdx.x;
  const int lane = tid & 63;
  const int w = tid >> 6;
  const int l15 = lane & 15, lg = lane >> 4;

  const int bid = blockIdx.x;
  const int kvh = bid & 7;
  const int hg = (bid >> 3) & 3;
  const int qi = 31 - (bid >> 5);
  const int h = kvh * 4 + hg;
  const int q0 = qi * 64;
  const int nt = qi + 1;

  const u16* Kg = qkv + NHEAD * HDIM + kvh * HDIM;
  const u16* Vg = qkv + (NHEAD + NKV) * HDIM + kvh * HDIM;

  bf16x8 qa[4];
  {
    const u16* qrow = qkv + (size_t)(q0 + w * 16 + l15) * QKVN + h * HDIM + lg * 8;
#pragma unroll
    for (int ks = 0; ks < 4; ++ks) qa[ks] = *(const bf16x8*)(qrow + ks * 32);
  }

  f32x4 acc_o[8] = {};
  float m[4], lsum[4];
#pragma unroll
  for (int r = 0; r < 4; ++r) { m[r] = -1e30f; lsum[r] = 0.f; }

  const float scale = 0.088388347648318447f;

#define STAGE_K(kv0, p)                                                        \
  {                                                                            \
    _Pragma("unroll") for (int rnd = 0; rnd < 4; ++rnd) {                      \
      int cc = rnd * 256 + tid;                                                \
      int krow = cc >> 4, kslot = cc & 15;                                     \
      gload16(Kg + (size_t)((kv0) + krow) * QKVN + (kslot ^ (krow & 7)) * 8,   \
              &Ksh[p][(rnd * 256 + w * 64) * 8]);                              \
    }                                                                          \
  }
#define LOAD_V(kv0, vr)                                                        \
  {                                                                            \
    _Pragma("unroll") for (int rnd = 0; rnd < 4; ++rnd) {                      \
      int cc = rnd * 256 + tid;                                                \
      int vrow = cc >> 4, d0 = (cc & 15) * 8;                                  \
      vr[rnd] = *(const u16x8*)(Vg + (size_t)((kv0) + vrow) * QKVN + d0);      \
    }                                                                          \
  }
#define WRITE_V(vr, p)                                                         \
  {                                                                            \
    _Pragma("unroll") for (int rnd = 0; rnd < 4; ++rnd) {                      \
      int cc = rnd * 256 + tid;                                                \
      int vrow = cc >> 4, d0 = (cc & 15) * 8;                                  \
      _Pragma("unroll") for (int j = 0; j < 8; ++j) {                          \
        int d = d0 + j;                                                        \
        Vsh[p][d * 64 + (((vrow >> 3) ^ (d & 7) ^ ((d >> 3) & 7)) * 8) +       \
               (vrow & 7)] = vr[rnd][j];                                       \
      }                                                                        \
    }                                                                          \
  }

  u16x8 vreg[4];
  STAGE_K(0, 0);
  LOAD_V(0, vreg);
  WRITE_V(vreg, 0);
  __syncthreads();

  for (int t = 0; t < nt; ++t) {
    const int p = t & 1;
    const int kv0 = t * 64;
    const bool more = (t + 1 < nt);
    u16x8 vnext[4];
    if (more) {
      STAGE_K(kv0 + 64, p ^ 1);
      LOAD_V(kv0 + 64, vnext);
    }

    f32x4 s[4] = {};
#pragma unroll
    for (int ks = 0; ks < 4; ++ks) {
#pragma unroll
      for (int n = 0; n < 4; ++n) {
        int row16 = n * 16 + l15;
        bf16x8 kf = *(const bf16x8*)&Ksh[p][row16 * 128 +
                                            (((ks * 4 + lg) ^ (row16 & 7)) * 8)];
        s[n] = __builtin_amdgcn_mfma_f32_16x16x32_bf16(qa[ks], kf, s[n], 0, 0, 0);
      }
    }

    const bool diag = (t == nt - 1);
    float alpha[4];
#pragma unroll
    for (int r = 0; r < 4; ++r) {
      int tq = q0 + w * 16 + lg * 4 + r;
      float mx = -1e30f;
#pragma unroll
      for (int n = 0; n < 4; ++n) {
        float v = s[n][r] * scale;
        if (diag && (kv0 + n * 16 + l15) > tq) v = -1e30f;
        s[n][r] = v;
        mx = fmaxf(mx, v);
      }
#pragma unroll
      for (int msk = 1; msk < 16; msk <<= 1) mx = fmaxf(mx, __shfl_xor(mx, msk, 64));
      float mn = fmaxf(m[r], mx);
      alpha[r] = __expf(m[r] - mn);
      m[r] = mn;
      float ps = 0.f;
#pragma unroll
      for (int n = 0; n < 4; ++n) {
        float pv = __expf(s[n][r] - mn);
        s[n][r] = pv;
        ps += pv;
      }
#pragma unroll
      for (int msk = 1; msk < 16; msk <<= 1) ps += __shfl_xor(ps, msk, 64);
      lsum[r] = lsum[r] * alpha[r] + ps;
      int prow = lg * 4 + r;
#pragma unroll
      for (int n = 0; n < 4; ++n)
        Psh[w][prow * 64 + (((n * 2 + (l15 >> 3)) ^ (prow & 7)) * 8) + (l15 & 7)] =
            f2bf(s[n][r]);
    }
#pragma unroll
    for (int f = 0; f < 8; ++f)
#pragma unroll
      for (int r = 0; r < 4; ++r) acc_o[f][r] *= alpha[r];

#pragma unroll
    for (int ks = 0; ks < 2; ++ks) {
      bf16x8 pa = *(const bf16x8*)&Psh[w][l15 * 64 + (((ks * 4 + lg) ^ (l15 & 7)) * 8)];
#pragma unroll
      for (int nd = 0; nd < 8; ++nd) {
        int d = nd * 16 + l15;
        bf16x8 bv = *(const bf16x8*)&Vsh[p][d * 64 +
                        (((ks * 4 + lg) ^ (d & 7) ^ ((d >> 3) & 7)) * 8)];
        acc_o[nd] = __builtin_amdgcn_mfma_f32_16x16x32_bf16(pa, bv, acc_o[nd], 0, 0, 0);
      }
    }

    if (more) WRITE_V(vnext, p ^ 1);
    __syncthreads();
  }

#pragma unroll
  for (int nd = 0; nd < 8; ++nd)
#pragma unroll
    for (int r = 0; r < 4; ++r) {
      int row = q0 + w * 16 + lg * 4 + r;
      int col = h * HDIM + nd * 16 + l15;
      out[(size_t)row * (NHEAD * HDIM) + col] = f2bf(acc_o[nd][r] / lsum[r]);
    }
#undef STAGE_K
#undef LOAD_V
#undef WRITE_V
}

// ---------------- launcher ----------------
extern "C" void kernel_launch(void* const* d_in, const int* in_sizes, int n_in,
                              void* d_out, int out_size, void* d_ws, size_t ws_size,
                              hipStream_t stream) {
  const float* hs   = (const float*)d_in[0];
  const int*   pos  = (const int*)d_in[1];
  const float* wqkv = (const float*)d_in[2];
  const float* wo   = (const float*)d_in[3];
  float* out = (float*)d_out;
  uint8_t* ws = (uint8_t*)d_ws;

  if (ws_size < 142606336u) return;
  u16* hs_bf   = (u16*)(ws + 0);
  u16* wqkv_bf = (u16*)(ws + 16777216u);
  u16* wo_bf   = (u16*)(ws + 67108864u);
  u16* qkv_bf  = (u16*)(ws + 100663296u);
  u16* attn_bf = (u16*)(ws + 125829120u);
  float* part  = (float*)(ws + 16777216u);  // reuse wqkv_bf (dead after QKV GEMM)

  cvt_f32_bf16<<<2048, 256, 0, stream>>>(hs, hs_bf, T_SEQ * HIDDEN);
  cvt_f32_bf16<<<2048, 256, 0, stream>>>(wqkv, wqkv_bf, QKVN * HIDDEN);

  // QKV: 8x24 = 192 GEMM blocks (256^2 tiles) + 64 blocks fused cvt of Wo
  gemm256<u16, true><<<256, 512, 0, stream>>>(
      hs_bf, wqkv_bf, qkv_bf, qkv_bf, QKVN, HIDDEN, 64,
      192, 192, 24, 3, 8, wo, wo_bf, (HIDDEN * HIDDEN) / 4);

  rope_kernel<<<(T_SEQ * 40 * 64) / 256, 256, 0, stream>>>(qkv_bf, pos);

  attn_kernel<<<1024, 256, 0, stream>>>(qkv_bf, attn_bf);

  // Wo: split-K=2, 2 x (8x16) = 256 blocks exact fill; slice1 -> part buffer
  gemm256<float, false><<<256, 512, 0, stream>>>(
      attn_bf, wo_bf, out, part, HIDDEN, HIDDEN, 32,
      128, 256, 16, 2, 8, nullptr, nullptr, 0);

  reduce_add<<<2048, 256, 0, stream>>>(out, part, (T_SEQ * HIDDEN) / 4);
}